// Round 3
// baseline (700.461 us; speedup 1.0000x reference)
//
#include <hip/hip_runtime.h>
#include <hip/hip_bf16.h>
#include <cstdint>

// Problem constants
#define BB  8
#define CH  64
#define TT  4096
#define KNN 9

#define NEG_INF (-3.402823466e38f)

// Workspace layout (float elements)
constexpr size_t OFF_QHAT = 0;                                    // [B][C][T]
constexpr size_t OFF_KHAT = (size_t)BB * CH * TT;                 //  2,097,152
constexpr size_t OFF_U    = OFF_KHAT + (size_t)BB * CH * TT;      //  4,194,304  u[B][9][T][C]
constexpr size_t OFF_CWP  = OFF_U + (size_t)BB * KNN * TT * CH;   // 23,068,672  cwp[9][64][64]
constexpr size_t OFF_PV   = OFF_CWP + (size_t)KNN * CH * CH;      // 23,105,536  pv[B][2][T][9]
constexpr size_t OFF_PI   = OFF_PV + (size_t)BB * 2 * TT * KNN;   // 23,695,360  pi[B][2][T][9]
constexpr size_t OFF_IDX  = OFF_PI + (size_t)BB * 2 * TT * KNN;   // 24,285,184  idx[B][T][9]

// ---------------------------------------------------------------------------
// sorted-9 ascending insert (s[0]=9th best). Caller guarantees w > s[0].
// ---------------------------------------------------------------------------
__device__ __forceinline__ void insert9(float w, int wi, float s[9], int si[9]) {
    bool c[9];
    c[0] = true;
    #pragma unroll
    for (int k = 1; k < 9; ++k) c[k] = w > s[k];
    #pragma unroll
    for (int k = 0; k < 8; ++k) si[k] = c[k + 1] ? si[k + 1] : (c[k] ? wi : si[k]);
    si[8] = c[8] ? wi : si[8];
    #pragma unroll
    for (int k = 0; k < 8; ++k) s[k] = __builtin_amdgcn_fmed3f(s[k], s[k + 1], w);
    s[8] = fmaxf(s[8], w);
}

// scan a batch of 8 candidates into list (s,si); batch-argmax prefilter.
__device__ __forceinline__ void scan8(float* a, int jcol0, float s[9], int si[9]) {
    float m = a[0]; int mj = 0;
    #pragma unroll
    for (int j = 1; j < 8; ++j) { bool g = a[j] > m; m = g ? a[j] : m; mj = g ? j : mj; }
    while (__any(m > s[0])) {
        if (m > s[0]) {
            insert9(m, jcol0 + mj, s, si);
            #pragma unroll
            for (int j = 0; j < 8; ++j) a[j] = (j == mj) ? NEG_INF : a[j];
        }
        m = a[0]; mj = 0;
        #pragma unroll
        for (int j = 1; j < 8; ++j) { bool g = a[j] > m; m = g ? a[j] : m; mj = g ? j : mj; }
    }
}

// merge the 8 per-lane lists of one row (8 consecutive lanes share a row).
__device__ __forceinline__ void merge8(float s[9], int si[9], float* pvrow, int* pirow) {
    #pragma unroll 1
    for (int m = 0; m < 9; ++m) {
        float hv = s[8]; int hi = si[8];
        #pragma unroll
        for (int d = 1; d < 8; d <<= 1) {
            float ov = __shfl_xor(hv, d);
            int   oi = __shfl_xor(hi, d);
            bool take = (ov > hv) || (ov == hv && oi < hi);
            hv = take ? ov : hv; hi = take ? oi : hi;
        }
        if (s[8] == hv && si[8] == hi) {
            pvrow[m] = hv; pirow[m] = hi;
            #pragma unroll
            for (int k = 8; k > 0; --k) { s[k] = s[k - 1]; si[k] = si[k - 1]; }
            s[0] = NEG_INF; si[0] = -1;
        }
    }
}

// ---------------------------------------------------------------------------
// K0: repack conv_w[o][cc*9+kk] -> cwp[kk][cc][o]
// ---------------------------------------------------------------------------
__global__ void repack_cw_kernel(const float* __restrict__ cw, float* __restrict__ cwp) {
    int e = blockIdx.x * blockDim.x + threadIdx.x;
    if (e >= KNN * CH * CH) return;
    int o  = e & 63;
    int cc = (e >> 6) & 63;
    int kk = e >> 12;
    cwp[e] = cw[o * (CH * KNN) + cc * KNN + kk];
}

// ---------------------------------------------------------------------------
// K1: QKV projection + L2 normalize + u-projection (unchanged, passing)
// ---------------------------------------------------------------------------
__global__ __launch_bounds__(256) void qkvu_kernel(
        const float* __restrict__ x,
        const float* __restrict__ Wq, const float* __restrict__ Wk, const float* __restrict__ Wv,
        const float* __restrict__ cwp,
        float* __restrict__ qhat, float* __restrict__ khat, float* __restrict__ u) {
    __shared__ __align__(16) float xs[CH * 64];
    __shared__ __align__(16) float vs[CH * 64];
    __shared__ __align__(16) float wl[CH * 64];
    __shared__ float pq[4 * 64], pk[4 * 64];

    const int b   = blockIdx.x >> 6;
    const int tb  = blockIdx.x & 63;
    const int tid = threadIdx.x;

    const float* xb = x + ((size_t)b * CH) * TT + tb * 64;
    #pragma unroll
    for (int m = 0; m < 16; ++m) {
        int l = tid + 256 * m;
        xs[l] = xb[(size_t)(l >> 6) * TT + (l & 63)];
    }
    __syncthreads();

    const int t = tid & 63;
    const int g = __builtin_amdgcn_readfirstlane(tid >> 6);
    const int d0 = g * 16;

    float qa[16], ka[16], va[16];
    #pragma unroll
    for (int dd = 0; dd < 16; ++dd) { qa[dd] = 0.f; ka[dd] = 0.f; va[dd] = 0.f; }

    #pragma unroll 4
    for (int c = 0; c < CH; ++c) {
        float xv = xs[c * 64 + t];
        #pragma unroll
        for (int dd = 0; dd < 16; ++dd) {
            qa[dd] = fmaf(Wq[(d0 + dd) * CH + c], xv, qa[dd]);
            ka[dd] = fmaf(Wk[(d0 + dd) * CH + c], xv, ka[dd]);
            va[dd] = fmaf(Wv[(d0 + dd) * CH + c], xv, va[dd]);
        }
    }

    float sq = 0.f, sk = 0.f;
    #pragma unroll
    for (int dd = 0; dd < 16; ++dd) { sq = fmaf(qa[dd], qa[dd], sq); sk = fmaf(ka[dd], ka[dd], sk); }
    pq[g * 64 + t] = sq;
    pk[g * 64 + t] = sk;
    __syncthreads();

    const float nq = sqrtf(pq[t] + pq[64 + t] + pq[128 + t] + pq[192 + t]);
    const float nk = sqrtf(pk[t] + pk[64 + t] + pk[128 + t] + pk[192 + t]);
    const float isq = 1.0f / fmaxf(nq, 1e-12f);
    const float isk = 1.0f / fmaxf(nk, 1e-12f);

    #pragma unroll
    for (int dd = 0; dd < 16; ++dd) {
        size_t go = ((size_t)b * CH + (d0 + dd)) * TT + tb * 64 + t;
        qhat[go] = qa[dd] * isq;
        khat[go] = ka[dd] * isk;
        vs[(d0 + dd) * 64 + t] = va[dd];
    }
    __syncthreads();

    const int to = tid & 15;
    const int tt = tid >> 4;
    for (int kk = 0; kk < KNN; ++kk) {
        #pragma unroll
        for (int m = 0; m < 16; ++m) {
            int l = tid + 256 * m;
            wl[l] = cwp[kk * (CH * CH) + l];
        }
        __syncthreads();
        float acc[4][4];
        #pragma unroll
        for (int i = 0; i < 4; ++i)
            #pragma unroll
            for (int j = 0; j < 4; ++j) acc[i][j] = 0.f;

        #pragma unroll 8
        for (int cc = 0; cc < CH; ++cc) {
            float4 wv = *(const float4*)&wl[cc * 64 + 4 * to];
            float4 vv = *(const float4*)&vs[cc * 64 + 4 * tt];
            const float wj[4] = {wv.x, wv.y, wv.z, wv.w};
            const float vi[4] = {vv.x, vv.y, vv.z, vv.w};
            #pragma unroll
            for (int i = 0; i < 4; ++i)
                #pragma unroll
                for (int j = 0; j < 4; ++j) acc[i][j] = fmaf(vi[i], wj[j], acc[i][j]);
        }
        #pragma unroll
        for (int i = 0; i < 4; ++i) {
            size_t row = (size_t)(b * KNN + kk) * TT + tb * 64 + 4 * tt + i;
            *(float4*)&u[row * CH + 4 * to] = make_float4(acc[i][0], acc[i][1], acc[i][2], acc[i][3]);
        }
        __syncthreads();
    }
}

// ---------------------------------------------------------------------------
// K2: fused sim GEMM (fp32) + register-resident streaming top-9
//     grid 512 = b(8, XCD swizzle) x ib(32) x jslice(2); block 256 (4 waves)
//     Per-thread 4 rows x 16 cols; 128x128 tile; LDS = kt 32K + qt 32K = 64 KB
//     -> 2 blocks/CU; LDS traffic 1.25 B/FMA (was 2.5).
// ---------------------------------------------------------------------------
__global__ __launch_bounds__(256, 2) void sim_topk_kernel(
        const float* __restrict__ qhat, const float* __restrict__ khat,
        float* __restrict__ pv, int* __restrict__ pi) {
    __shared__ __align__(16) float kt[CH * 128];   // kt[c][i]
    __shared__ __align__(16) float qt[CH * 128];   // qt[c][j]

    const int b   = blockIdx.x & 7;
    const int ib  = (blockIdx.x >> 3) & 31;
    const int js  = blockIdx.x >> 8;              // 0..1
    const int tid = threadIdx.x;

    // stage k-tile [c][128 rows], float4 coalesced
    const float* kb = khat + ((size_t)b * CH) * TT + ib * 128;
    #pragma unroll
    for (int m = 0; m < 8; ++m) {
        int f = tid + 256 * m;             // float4 index
        int c = f >> 5, i4 = (f & 31) * 4;
        *(float4*)&kt[c * 128 + i4] = *(const float4*)&kb[(size_t)c * TT + i4];
    }

    const int ti = tid >> 3;   // 0..31 -> rows 4ti..4ti+3
    const int tj = tid & 7;    // cols 16tj..16tj+15

    float s[4][9]; int si[4][9];
    #pragma unroll
    for (int r = 0; r < 4; ++r)
        #pragma unroll
        for (int k = 0; k < 9; ++k) { s[r][k] = NEG_INF; si[r][k] = 0; }

    const float* qb = qhat + ((size_t)b * CH) * TT + js * 2048;

    for (int jt = 0; jt < 16; ++jt) {
        #pragma unroll
        for (int m = 0; m < 8; ++m) {
            int f = tid + 256 * m;
            int c = f >> 5, j4 = (f & 31) * 4;
            *(float4*)&qt[c * 128 + j4] = *(const float4*)&qb[(size_t)c * TT + jt * 128 + j4];
        }
        __syncthreads();

        float acc[4][16];
        #pragma unroll
        for (int r = 0; r < 4; ++r)
            #pragma unroll
            for (int j = 0; j < 16; ++j) acc[r][j] = 0.f;

        #pragma unroll 4
        for (int c = 0; c < CH; ++c) {
            float4 kv = *(const float4*)&kt[c * 128 + 4 * ti];
            float4 q0 = *(const float4*)&qt[c * 128 + 16 * tj];
            float4 q1 = *(const float4*)&qt[c * 128 + 16 * tj + 4];
            float4 q2 = *(const float4*)&qt[c * 128 + 16 * tj + 8];
            float4 q3 = *(const float4*)&qt[c * 128 + 16 * tj + 12];
            const float kr[4] = {kv.x, kv.y, kv.z, kv.w};
            const float qv[16] = {q0.x, q0.y, q0.z, q0.w, q1.x, q1.y, q1.z, q1.w,
                                  q2.x, q2.y, q2.z, q2.w, q3.x, q3.y, q3.z, q3.w};
            #pragma unroll
            for (int r = 0; r < 4; ++r)
                #pragma unroll
                for (int j = 0; j < 16; ++j)
                    acc[r][j] = fmaf(kr[r], qv[j], acc[r][j]);
        }
        __syncthreads();   // qt consumed; scan below is register-only

        const int j0 = js * 2048 + jt * 128 + 16 * tj;
        #pragma unroll
        for (int r = 0; r < 4; ++r) {
            scan8(&acc[r][0], j0,     s[r], si[r]);
            scan8(&acc[r][8], j0 + 8, s[r], si[r]);
        }
    }

    // per-row merge of the 8 per-lane lists (shfl over lanes sharing ti)
    const int gi = ib * 128 + 4 * ti;
    float* pv0 = pv + (((size_t)(b * 2 + js)) * TT + gi) * KNN;
    int*   pi0 = pi + (((size_t)(b * 2 + js)) * TT + gi) * KNN;
    #pragma unroll 1
    for (int r = 0; r < 4; ++r)
        merge8(s[r], si[r], pv0 + r * KNN, pi0 + r * KNN);
}

// ---------------------------------------------------------------------------
// K2b: merge the 2 j-slice partial lists per row -> final idx[b][t][9]
// ---------------------------------------------------------------------------
__global__ __launch_bounds__(256) void merge_slices_kernel(
        const float* __restrict__ pv, const int* __restrict__ pi,
        int* __restrict__ idxout) {
    int r = blockIdx.x * blockDim.x + threadIdx.x;
    if (r >= BB * TT) return;
    int b = r >> 12, i = r & (TT - 1);

    float s[9]; int si[9];
    #pragma unroll
    for (int k = 0; k < 9; ++k) { s[k] = NEG_INF; si[k] = 0; }

    #pragma unroll
    for (int js = 0; js < 2; ++js) {
        const float* pvr = pv + (((size_t)(b * 2 + js)) * TT + i) * KNN;
        const int*   pir = pi + (((size_t)(b * 2 + js)) * TT + i) * KNN;
        #pragma unroll
        for (int m = 0; m < 9; ++m) {
            float w = pvr[m]; int wi = pir[m];
            if (w > s[0]) insert9(w, wi, s, si);
        }
    }
    int* orow = idxout + ((size_t)b * TT + i) * KNN;
    #pragma unroll
    for (int m = 0; m < 9; ++m) orow[m] = si[8 - m];
}

// ---------------------------------------------------------------------------
// K3: out[b][o][t] = conv_b[o] + sum_kk u[b][kk][idx[b][t][kk]][o]
// ---------------------------------------------------------------------------
__global__ __launch_bounds__(256) void gather_conv_kernel(
        const float* __restrict__ u, const int* __restrict__ idxin,
        const float* __restrict__ conv_b, float* __restrict__ out) {
    __shared__ int   sidx[64 * KNN];
    __shared__ float cb[CH];
    const int b   = blockIdx.x & 7;
    const int tb  = blockIdx.x >> 3;
    const int tid = threadIdx.x;

    if (tid < CH) cb[tid] = conv_b[tid];
    const int* ig = idxin + ((size_t)b * TT + tb * 64) * KNN;
    for (int l = tid; l < 64 * KNN; l += 256) sidx[l] = ig[l];
    __syncthreads();

    const int tl = tid & 63;
    const int og = tid >> 6;
    const int o0 = og * 16;

    float acc[16];
    #pragma unroll
    for (int q = 0; q < 16; ++q) acc[q] = cb[o0 + q];

    #pragma unroll
    for (int kk = 0; kk < KNN; ++kk) {
        int j = sidx[tl * KNN + kk];
        const float* up = u + (((size_t)(b * KNN + kk)) * TT + j) * CH + o0;
        #pragma unroll
        for (int q4 = 0; q4 < 4; ++q4) {
            float4 uv = *(const float4*)&up[q4 * 4];
            acc[q4 * 4 + 0] += uv.x;
            acc[q4 * 4 + 1] += uv.y;
            acc[q4 * 4 + 2] += uv.z;
            acc[q4 * 4 + 3] += uv.w;
        }
    }
    const int t = tb * 64 + tl;
    #pragma unroll
    for (int q = 0; q < 16; ++q)
        out[((size_t)b * CH + o0 + q) * TT + t] = acc[q];
}

// ---------------------------------------------------------------------------
extern "C" void kernel_launch(void* const* d_in, const int* in_sizes, int n_in,
                              void* d_out, int out_size, void* d_ws, size_t ws_size,
                              hipStream_t stream) {
    const float* x   = (const float*)d_in[0];
    const float* Wq  = (const float*)d_in[1];
    const float* Wk  = (const float*)d_in[2];
    const float* Wv  = (const float*)d_in[3];
    const float* cw  = (const float*)d_in[4];
    const float* cbp = (const float*)d_in[5];

    float* ws   = (float*)d_ws;
    float* qhat = ws + OFF_QHAT;
    float* khat = ws + OFF_KHAT;
    float* u    = ws + OFF_U;
    float* cwp  = ws + OFF_CWP;
    float* pv   = ws + OFF_PV;
    int*   pi   = (int*)(ws + OFF_PI);
    int*   idx  = (int*)(ws + OFF_IDX);
    float* out  = (float*)d_out;

    repack_cw_kernel<<<(KNN * CH * CH + 255) / 256, 256, 0, stream>>>(cw, cwp);
    qkvu_kernel<<<BB * 64, 256, 0, stream>>>(x, Wq, Wk, Wv, cwp, qhat, khat, u);
    sim_topk_kernel<<<BB * 32 * 2, 256, 0, stream>>>(qhat, khat, pv, pi);
    merge_slices_kernel<<<(BB * TT + 255) / 256, 256, 0, stream>>>(pv, pi, idx);
    gather_conv_kernel<<<BB * 64, 256, 0, stream>>>(u, idx, cbp, out);
}

// Round 4
// 523.156 us; speedup vs baseline: 1.3389x; 1.3389x over previous
//
#include <hip/hip_runtime.h>
#include <hip/hip_bf16.h>
#include <cstdint>

// Problem constants
#define BB  8
#define CH  64
#define TT  4096
#define KNN 9

#define NEG_INF (-3.402823466e38f)

// qt padded layout: 8 groups of 16 cols, each group padded to 20 floats.
#define QSTRIDE 160

// Workspace layout (float elements)
constexpr size_t OFF_QHAT = 0;                                    // [B][C][T]
constexpr size_t OFF_KHAT = (size_t)BB * CH * TT;
constexpr size_t OFF_U    = OFF_KHAT + (size_t)BB * CH * TT;      // u[B][9][T][C]
constexpr size_t OFF_CWP  = OFF_U + (size_t)BB * KNN * TT * CH;   // cwp[9][64][64]
constexpr size_t OFF_PV   = OFF_CWP + (size_t)KNN * CH * CH;      // pv[B][2][T][9]
constexpr size_t OFF_PI   = OFF_PV + (size_t)BB * 2 * TT * KNN;   // pi[B][2][T][9]
constexpr size_t OFF_IDX  = OFF_PI + (size_t)BB * 2 * TT * KNN;   // idx[B][T][9]

// ---------------------------------------------------------------------------
// sorted-9 ascending insert (s[0]=9th best). Caller guarantees w > s[0].
// Reference params keep SROA intact (round-3 lesson: any runtime index or
// opaque pointer into these arrays spills them to scratch -> 664 MB traffic).
// ---------------------------------------------------------------------------
__device__ __forceinline__ void insert9(float w, int wi, float (&s)[9], int (&si)[9]) {
    bool c[9];
    c[0] = true;
    #pragma unroll
    for (int k = 1; k < 9; ++k) c[k] = w > s[k];
    #pragma unroll
    for (int k = 0; k < 8; ++k) si[k] = c[k + 1] ? si[k + 1] : (c[k] ? wi : si[k]);
    si[8] = c[8] ? wi : si[8];
    #pragma unroll
    for (int k = 0; k < 8; ++k) s[k] = __builtin_amdgcn_fmed3f(s[k], s[k + 1], w);
    s[8] = fmaxf(s[8], w);
}

// scan one 16-wide acc row into list (s,si); batch-argmax prefilter.
__device__ __forceinline__ void scan16(float (&a)[16], int jcol0, float (&s)[9], int (&si)[9]) {
    float m = a[0]; int mj = 0;
    #pragma unroll
    for (int j = 1; j < 16; ++j) { bool g = a[j] > m; m = g ? a[j] : m; mj = g ? j : mj; }
    while (__any(m > s[0])) {
        if (m > s[0]) {
            insert9(m, jcol0 + mj, s, si);
            #pragma unroll
            for (int j = 0; j < 16; ++j) a[j] = (j == mj) ? NEG_INF : a[j];
        }
        m = a[0]; mj = 0;
        #pragma unroll
        for (int j = 1; j < 16; ++j) { bool g = a[j] > m; m = g ? a[j] : m; mj = g ? j : mj; }
    }
}

// merge the 8 per-lane lists of one row (8 consecutive lanes share a row).
// Dynamic m only indexes global pointers; register arrays stay static-indexed.
__device__ __forceinline__ void merge8(float (&s)[9], int (&si)[9], float* pvrow, int* pirow) {
    #pragma unroll 1
    for (int m = 0; m < 9; ++m) {
        float hv = s[8]; int hi = si[8];
        #pragma unroll
        for (int d = 1; d < 8; d <<= 1) {
            float ov = __shfl_xor(hv, d);
            int   oi = __shfl_xor(hi, d);
            bool take = (ov > hv) || (ov == hv && oi < hi);
            hv = take ? ov : hv; hi = take ? oi : hi;
        }
        if (s[8] == hv && si[8] == hi) {
            pvrow[m] = hv; pirow[m] = hi;
            #pragma unroll
            for (int k = 8; k > 0; --k) { s[k] = s[k - 1]; si[k] = si[k - 1]; }
            s[0] = NEG_INF; si[0] = -1;
        }
    }
}

// ---------------------------------------------------------------------------
// K0: repack conv_w[o][cc*9+kk] -> cwp[kk][cc][o]
// ---------------------------------------------------------------------------
__global__ void repack_cw_kernel(const float* __restrict__ cw, float* __restrict__ cwp) {
    int e = blockIdx.x * blockDim.x + threadIdx.x;
    if (e >= KNN * CH * CH) return;
    int o  = e & 63;
    int cc = (e >> 6) & 63;
    int kk = e >> 12;
    cwp[e] = cw[o * (CH * KNN) + cc * KNN + kk];
}

// ---------------------------------------------------------------------------
// K1: QKV projection + L2 normalize + u-projection (unchanged, passing)
// ---------------------------------------------------------------------------
__global__ __launch_bounds__(256) void qkvu_kernel(
        const float* __restrict__ x,
        const float* __restrict__ Wq, const float* __restrict__ Wk, const float* __restrict__ Wv,
        const float* __restrict__ cwp,
        float* __restrict__ qhat, float* __restrict__ khat, float* __restrict__ u) {
    __shared__ __align__(16) float xs[CH * 64];
    __shared__ __align__(16) float vs[CH * 64];
    __shared__ __align__(16) float wl[CH * 64];
    __shared__ float pq[4 * 64], pk[4 * 64];

    const int b   = blockIdx.x >> 6;
    const int tb  = blockIdx.x & 63;
    const int tid = threadIdx.x;

    const float* xb = x + ((size_t)b * CH) * TT + tb * 64;
    #pragma unroll
    for (int m = 0; m < 16; ++m) {
        int l = tid + 256 * m;
        xs[l] = xb[(size_t)(l >> 6) * TT + (l & 63)];
    }
    __syncthreads();

    const int t = tid & 63;
    const int g = __builtin_amdgcn_readfirstlane(tid >> 6);
    const int d0 = g * 16;

    float qa[16], ka[16], va[16];
    #pragma unroll
    for (int dd = 0; dd < 16; ++dd) { qa[dd] = 0.f; ka[dd] = 0.f; va[dd] = 0.f; }

    #pragma unroll 4
    for (int c = 0; c < CH; ++c) {
        float xv = xs[c * 64 + t];
        #pragma unroll
        for (int dd = 0; dd < 16; ++dd) {
            qa[dd] = fmaf(Wq[(d0 + dd) * CH + c], xv, qa[dd]);
            ka[dd] = fmaf(Wk[(d0 + dd) * CH + c], xv, ka[dd]);
            va[dd] = fmaf(Wv[(d0 + dd) * CH + c], xv, va[dd]);
        }
    }

    float sq = 0.f, sk = 0.f;
    #pragma unroll
    for (int dd = 0; dd < 16; ++dd) { sq = fmaf(qa[dd], qa[dd], sq); sk = fmaf(ka[dd], ka[dd], sk); }
    pq[g * 64 + t] = sq;
    pk[g * 64 + t] = sk;
    __syncthreads();

    const float nq = sqrtf(pq[t] + pq[64 + t] + pq[128 + t] + pq[192 + t]);
    const float nk = sqrtf(pk[t] + pk[64 + t] + pk[128 + t] + pk[192 + t]);
    const float isq = 1.0f / fmaxf(nq, 1e-12f);
    const float isk = 1.0f / fmaxf(nk, 1e-12f);

    #pragma unroll
    for (int dd = 0; dd < 16; ++dd) {
        size_t go = ((size_t)b * CH + (d0 + dd)) * TT + tb * 64 + t;
        qhat[go] = qa[dd] * isq;
        khat[go] = ka[dd] * isk;
        vs[(d0 + dd) * 64 + t] = va[dd];
    }
    __syncthreads();

    const int to = tid & 15;
    const int tt = tid >> 4;
    for (int kk = 0; kk < KNN; ++kk) {
        #pragma unroll
        for (int m = 0; m < 16; ++m) {
            int l = tid + 256 * m;
            wl[l] = cwp[kk * (CH * CH) + l];
        }
        __syncthreads();
        float acc[4][4];
        #pragma unroll
        for (int i = 0; i < 4; ++i)
            #pragma unroll
            for (int j = 0; j < 4; ++j) acc[i][j] = 0.f;

        #pragma unroll 8
        for (int cc = 0; cc < CH; ++cc) {
            float4 wv = *(const float4*)&wl[cc * 64 + 4 * to];
            float4 vv = *(const float4*)&vs[cc * 64 + 4 * tt];
            const float wj[4] = {wv.x, wv.y, wv.z, wv.w};
            const float vi[4] = {vv.x, vv.y, vv.z, vv.w};
            #pragma unroll
            for (int i = 0; i < 4; ++i)
                #pragma unroll
                for (int j = 0; j < 4; ++j) acc[i][j] = fmaf(vi[i], wj[j], acc[i][j]);
        }
        #pragma unroll
        for (int i = 0; i < 4; ++i) {
            size_t row = (size_t)(b * KNN + kk) * TT + tb * 64 + 4 * tt + i;
            *(float4*)&u[row * CH + 4 * to] = make_float4(acc[i][0], acc[i][1], acc[i][2], acc[i][3]);
        }
        __syncthreads();
    }
}

// ---------------------------------------------------------------------------
// K2: fused sim GEMM (fp32) + register-resident streaming top-9
//     grid 512 = b(8, XCD swizzle) x ib(32) x jslice(2); block 256 (4 waves)
//     Per-thread 4 rows x 16 cols; 128x128 tile.
//     kt row stride 128 (reads conflict-free: 16-B lane stride).
//     qt row stride 160, 16-col groups padded to 20 -> q-read banks
//     {0,20,8,28,16,4,24,12}*4: conflict-free.
//     LDS = 32K + 40K = 72 KB -> 2 blocks/CU.
// ---------------------------------------------------------------------------
__global__ __launch_bounds__(256, 2) void sim_topk_kernel(
        const float* __restrict__ qhat, const float* __restrict__ khat,
        float* __restrict__ pv, int* __restrict__ pi) {
    __shared__ __align__(16) float kt[CH * 128];       // kt[c][i]
    __shared__ __align__(16) float qt[CH * QSTRIDE];   // qt[c][padded j]

    const int b   = blockIdx.x & 7;
    const int ib  = (blockIdx.x >> 3) & 31;
    const int js  = blockIdx.x >> 8;              // 0..1
    const int tid = threadIdx.x;

    // stage k-tile [c][128 rows], float4 coalesced
    const float* kb = khat + ((size_t)b * CH) * TT + ib * 128;
    #pragma unroll
    for (int m = 0; m < 8; ++m) {
        int f = tid + 256 * m;             // float4 index
        int c = f >> 5, i4 = (f & 31) * 4;
        *(float4*)&kt[c * 128 + i4] = *(const float4*)&kb[(size_t)c * TT + i4];
    }

    const int ti = tid >> 3;   // 0..31 -> rows 4ti..4ti+3
    const int tj = tid & 7;    // col group: 16 cols at 16*tj, padded base 20*tj

    float s[4][9]; int si[4][9];
    #pragma unroll
    for (int r = 0; r < 4; ++r)
        #pragma unroll
        for (int k = 0; k < 9; ++k) { s[r][k] = NEG_INF; si[r][k] = 0; }

    const float* qb = qhat + ((size_t)b * CH) * TT + js * 2048;

    for (int jt = 0; jt < 16; ++jt) {
        #pragma unroll
        for (int m = 0; m < 8; ++m) {
            int f = tid + 256 * m;
            int c = f >> 5, j4 = (f & 31) * 4;
            int goff = (j4 >> 4) * 20 + (j4 & 15);   // padded group layout
            *(float4*)&qt[c * QSTRIDE + goff] = *(const float4*)&qb[(size_t)c * TT + jt * 128 + j4];
        }
        __syncthreads();

        float acc[4][16];
        #pragma unroll
        for (int r = 0; r < 4; ++r)
            #pragma unroll
            for (int j = 0; j < 16; ++j) acc[r][j] = 0.f;

        #pragma unroll 2
        for (int c = 0; c < CH; ++c) {
            float4 kv = *(const float4*)&kt[c * 128 + 4 * ti];
            float4 q0 = *(const float4*)&qt[c * QSTRIDE + 20 * tj];
            float4 q1 = *(const float4*)&qt[c * QSTRIDE + 20 * tj + 4];
            float4 q2 = *(const float4*)&qt[c * QSTRIDE + 20 * tj + 8];
            float4 q3 = *(const float4*)&qt[c * QSTRIDE + 20 * tj + 12];
            const float kr[4] = {kv.x, kv.y, kv.z, kv.w};
            const float qv[16] = {q0.x, q0.y, q0.z, q0.w, q1.x, q1.y, q1.z, q1.w,
                                  q2.x, q2.y, q2.z, q2.w, q3.x, q3.y, q3.z, q3.w};
            #pragma unroll
            for (int r = 0; r < 4; ++r)
                #pragma unroll
                for (int j = 0; j < 16; ++j)
                    acc[r][j] = fmaf(kr[r], qv[j], acc[r][j]);
        }
        __syncthreads();   // qt consumed; scan below is register-only

        const int j0 = js * 2048 + jt * 128 + 16 * tj;
        scan16(acc[0], j0, s[0], si[0]);
        scan16(acc[1], j0, s[1], si[1]);
        scan16(acc[2], j0, s[2], si[2]);
        scan16(acc[3], j0, s[3], si[3]);
    }

    // per-row merge of the 8 per-lane lists (shfl over lanes sharing ti)
    const int gi = ib * 128 + 4 * ti;
    float* pv0 = pv + (((size_t)(b * 2 + js)) * TT + gi) * KNN;
    int*   pi0 = pi + (((size_t)(b * 2 + js)) * TT + gi) * KNN;
    merge8(s[0], si[0], pv0,           pi0);
    merge8(s[1], si[1], pv0 + KNN,     pi0 + KNN);
    merge8(s[2], si[2], pv0 + 2 * KNN, pi0 + 2 * KNN);
    merge8(s[3], si[3], pv0 + 3 * KNN, pi0 + 3 * KNN);
}

// ---------------------------------------------------------------------------
// K2b: merge the 2 j-slice partial lists per row -> final idx[b][t][9]
// ---------------------------------------------------------------------------
__global__ __launch_bounds__(256) void merge_slices_kernel(
        const float* __restrict__ pv, const int* __restrict__ pi,
        int* __restrict__ idxout) {
    int r = blockIdx.x * blockDim.x + threadIdx.x;
    if (r >= BB * TT) return;
    int b = r >> 12, i = r & (TT - 1);

    float s[9]; int si[9];
    #pragma unroll
    for (int k = 0; k < 9; ++k) { s[k] = NEG_INF; si[k] = 0; }

    #pragma unroll
    for (int js = 0; js < 2; ++js) {
        const float* pvr = pv + (((size_t)(b * 2 + js)) * TT + i) * KNN;
        const int*   pir = pi + (((size_t)(b * 2 + js)) * TT + i) * KNN;
        #pragma unroll
        for (int m = 0; m < 9; ++m) {
            float w = pvr[m]; int wi = pir[m];
            if (w > s[0]) insert9(w, wi, s, si);
        }
    }
    int* orow = idxout + ((size_t)b * TT + i) * KNN;
    #pragma unroll
    for (int m = 0; m < 9; ++m) orow[m] = si[8 - m];
}

// ---------------------------------------------------------------------------
// K3: out[b][o][t] = conv_b[o] + sum_kk u[b][kk][idx[b][t][kk]][o]
// ---------------------------------------------------------------------------
__global__ __launch_bounds__(256) void gather_conv_kernel(
        const float* __restrict__ u, const int* __restrict__ idxin,
        const float* __restrict__ conv_b, float* __restrict__ out) {
    __shared__ int   sidx[64 * KNN];
    __shared__ float cb[CH];
    const int b   = blockIdx.x & 7;
    const int tb  = blockIdx.x >> 3;
    const int tid = threadIdx.x;

    if (tid < CH) cb[tid] = conv_b[tid];
    const int* ig = idxin + ((size_t)b * TT + tb * 64) * KNN;
    for (int l = tid; l < 64 * KNN; l += 256) sidx[l] = ig[l];
    __syncthreads();

    const int tl = tid & 63;
    const int og = tid >> 6;
    const int o0 = og * 16;

    float acc[16];
    #pragma unroll
    for (int q = 0; q < 16; ++q) acc[q] = cb[o0 + q];

    #pragma unroll
    for (int kk = 0; kk < KNN; ++kk) {
        int j = sidx[tl * KNN + kk];
        const float* up = u + (((size_t)(b * KNN + kk)) * TT + j) * CH + o0;
        #pragma unroll
        for (int q4 = 0; q4 < 4; ++q4) {
            float4 uv = *(const float4*)&up[q4 * 4];
            acc[q4 * 4 + 0] += uv.x;
            acc[q4 * 4 + 1] += uv.y;
            acc[q4 * 4 + 2] += uv.z;
            acc[q4 * 4 + 3] += uv.w;
        }
    }
    const int t = tb * 64 + tl;
    #pragma unroll
    for (int q = 0; q < 16; ++q)
        out[((size_t)b * CH + o0 + q) * TT + t] = acc[q];
}

// ---------------------------------------------------------------------------
extern "C" void kernel_launch(void* const* d_in, const int* in_sizes, int n_in,
                              void* d_out, int out_size, void* d_ws, size_t ws_size,
                              hipStream_t stream) {
    const float* x   = (const float*)d_in[0];
    const float* Wq  = (const float*)d_in[1];
    const float* Wk  = (const float*)d_in[2];
    const float* Wv  = (const float*)d_in[3];
    const float* cw  = (const float*)d_in[4];
    const float* cbp = (const float*)d_in[5];

    float* ws   = (float*)d_ws;
    float* qhat = ws + OFF_QHAT;
    float* khat = ws + OFF_KHAT;
    float* u    = ws + OFF_U;
    float* cwp  = ws + OFF_CWP;
    float* pv   = ws + OFF_PV;
    int*   pi   = (int*)(ws + OFF_PI);
    int*   idx  = (int*)(ws + OFF_IDX);
    float* out  = (float*)d_out;

    repack_cw_kernel<<<(KNN * CH * CH + 255) / 256, 256, 0, stream>>>(cw, cwp);
    qkvu_kernel<<<BB * 64, 256, 0, stream>>>(x, Wq, Wk, Wv, cwp, qhat, khat, u);
    sim_topk_kernel<<<BB * 32 * 2, 256, 0, stream>>>(qhat, khat, pv, pi);
    merge_slices_kernel<<<(BB * TT + 255) / 256, 256, 0, stream>>>(pv, pi, idx);
    gather_conv_kernel<<<BB * 64, 256, 0, stream>>>(u, idx, cbp, out);
}